// Round 1
// baseline (133.411 us; speedup 1.0000x reference)
//
#include <hip/hip_runtime.h>

// Problem constants: B,H,W,C = 16,256,256,16 ; HO,WO = 256,256
#define BB 16
#define HH 256
#define WW 256
#define CC 16
#define NPIX (HH * WW)            // 65536 pixels per batch
#define SLICES 128                // pool slices per batch
#define POOL_BLOCKS (BB * SLICES) // 2048 blocks
#define SAMPLE_BLOCKS (BB * 128)  // 2048 blocks

typedef float vf4 __attribute__((ext_vector_type(4)));

// ---------------------------------------------------------------------------
// Kernel 1: partial mean-pool. 2048 blocks, 256 threads. Unchanged (already
// at the HBM read floor: 64 MiB coalesced float4 stream).
// ---------------------------------------------------------------------------
__global__ __launch_bounds__(256) void pool_partial(const float4* __restrict__ x4,
                                                    float4* __restrict__ part) {
    const int blk = blockIdx.x;
    const int tid = threadIdx.x;
    const float4* p = x4 + (size_t)blk * 2048 + tid;
    float4 acc = {0.f, 0.f, 0.f, 0.f};
#pragma unroll
    for (int k = 0; k < 8; ++k) {
        float4 v = p[k * 256];
        acc.x += v.x; acc.y += v.y; acc.z += v.z; acc.w += v.w;
    }
    // Lanes with equal (lane&3) share a channel quad.
    for (int off = 4; off < 64; off <<= 1) {
        acc.x += __shfl_down(acc.x, off);
        acc.y += __shfl_down(acc.y, off);
        acc.z += __shfl_down(acc.z, off);
        acc.w += __shfl_down(acc.w, off);
    }
    __shared__ float4 wsum[4][4];
    const int wave = tid >> 6, lane = tid & 63;
    if (lane < 4) wsum[wave][lane] = acc;
    __syncthreads();
    if (tid < 4) {
        float4 t0 = wsum[0][tid], t1 = wsum[1][tid];
        float4 t2 = wsum[2][tid], t3 = wsum[3][tid];
        float4 t;
        t.x = t0.x + t1.x + t2.x + t3.x;
        t.y = t0.y + t1.y + t2.y + t3.y;
        t.z = t0.z + t1.z + t2.z + t3.z;
        t.w = t0.w + t1.w + t2.w + t3.w;
        part[blk * 4 + tid] = t;
    }
}

// ---------------------------------------------------------------------------
// Kernel 2: params. 16 blocks (one per batch), 256 threads. Reduces that
// batch's 512 float4 partials and emits the 6 affine params. Hoisted out of
// the sample kernel so 2048 sample blocks don't each redo an 8 KB reduce +
// 3 barriers before their first gather.
// ---------------------------------------------------------------------------
__global__ __launch_bounds__(256) void params_kernel(const float4* __restrict__ part,
                                                     const float* __restrict__ W_loc,
                                                     const float* __restrict__ b_loc,
                                                     float* __restrict__ prm) {
    const int b   = blockIdx.x;
    const int tid = threadIdx.x;
    const int wave = tid >> 6, lane = tid & 63;
    __shared__ float4 wsum[4][4];
    __shared__ float  pooled[CC];

    const float4* q = part + (size_t)b * 512;
    float4 a0 = q[tid], a1 = q[tid + 256];
    float4 acc;
    acc.x = a0.x + a1.x; acc.y = a0.y + a1.y;
    acc.z = a0.z + a1.z; acc.w = a0.w + a1.w;
    for (int off = 4; off < 64; off <<= 1) {
        acc.x += __shfl_down(acc.x, off);
        acc.y += __shfl_down(acc.y, off);
        acc.z += __shfl_down(acc.z, off);
        acc.w += __shfl_down(acc.w, off);
    }
    if (lane < 4) wsum[wave][lane] = acc;
    __syncthreads();
    if (tid < 4) {
        float4 t0 = wsum[0][tid], t1 = wsum[1][tid];
        float4 t2 = wsum[2][tid], t3 = wsum[3][tid];
        pooled[tid * 4 + 0] = (t0.x + t1.x + t2.x + t3.x) * (1.0f / 65536.0f);
        pooled[tid * 4 + 1] = (t0.y + t1.y + t2.y + t3.y) * (1.0f / 65536.0f);
        pooled[tid * 4 + 2] = (t0.z + t1.z + t2.z + t3.z) * (1.0f / 65536.0f);
        pooled[tid * 4 + 3] = (t0.w + t1.w + t2.w + t3.w) * (1.0f / 65536.0f);
    }
    __syncthreads();
    if (tid < 6) {
        float a = b_loc[tid];
#pragma unroll
        for (int c = 0; c < CC; ++c)
            a += pooled[c] * W_loc[c * 6 + tid];
        prm[b * 8 + tid] = a;
    }
}

// ---------------------------------------------------------------------------
// Kernel 3: bilinear sampling. 2048 blocks, 256 threads; block = 512 pixels
// (2 output rows) of one batch; 4 lanes per pixel (one float4 channel quad
// each); 8 pixel-quads per thread.
//  - params read as 6 uniform scalars (s_load), no LDS, no barriers.
//  - all gather/store addressing is 32-bit byte offsets off a wave-uniform
//    batch base (offsets < 4 MiB) -> SGPR base + VGPR voffset loads, no
//    64-bit VALU chains in the loop.
//  - non-temporal stores: output is write-once, keep it out of the L2/L3
//    the x gathers hit.
// ---------------------------------------------------------------------------
__global__ __launch_bounds__(256) void sample_v2(const char* __restrict__ xb0,
                                                 const float* __restrict__ prm,
                                                 char* __restrict__ ob0) {
    const int tid = threadIdx.x;
    const int blk = blockIdx.x;          // b*128 + local
    const int b   = blk >> 7;

    const float* pp = prm + b * 8;       // uniform address -> scalar loads
    const float p0 = pp[0], p1 = pp[1], p2 = pp[2];
    const float p3 = pp[3], p4 = pp[4], p5 = pp[5];

    const char* xb = xb0 + ((size_t)b << 22);   // batch base: 4 MiB per batch
    char*       ob = ob0 + ((size_t)b << 22);
    const unsigned int cqo = (unsigned int)(tid & 3) << 4;  // channel-quad byte off

    const int pixBase = (blk & 127) * 512 + (tid >> 2);
    const int h0 = (blk & 127) * 2;
    const int w0 = tid >> 2;

#pragma unroll 4
    for (int k = 0; k < 8; ++k) {
        const int hh  = h0 + (k >> 2);
        const int wpx = w0 + ((k & 3) << 6);

        const float fh = (float)hh, fw = (float)wpx;
        const float yc = p0 * fh + p1 * fw + p4;
        const float xc = p2 * fh + p3 * fw + p5;

        const float y0f = floorf(yc), x0f = floorf(xc);
        const float wy = yc - y0f, wx = xc - x0f;
        const int y0 = (int)y0f, x0v = (int)x0f;
        const int y0i = min(max(y0,     0), HH - 1);
        const int y1i = min(max(y0 + 1, 0), HH - 1);
        const int x0i = min(max(x0v,     0), WW - 1);
        const int x1i = min(max(x0v + 1, 0), WW - 1);

        const unsigned int r0 = ((unsigned int)y0i << 14) + cqo;  // y*W*C*4
        const unsigned int r1 = ((unsigned int)y1i << 14) + cqo;
        const unsigned int c0 = (unsigned int)x0i << 6;           // x*C*4
        const unsigned int c1 = (unsigned int)x1i << 6;

        const vf4 Ia = *(const vf4*)(xb + (r0 + c0));
        const vf4 Ib = *(const vf4*)(xb + (r0 + c1));
        const vf4 Ic = *(const vf4*)(xb + (r1 + c0));
        const vf4 Id = *(const vf4*)(xb + (r1 + c1));

        const float omy = 1.f - wy, omx = 1.f - wx;
        const float wa = omy * omx, wb_ = omy * wx;
        const float wc_ = wy * omx, wd = wy * wx;

        vf4 o = wa * Ia + wb_ * Ib + wc_ * Ic + wd * Id;

        const unsigned int po = ((unsigned int)(pixBase + (k << 6)) << 6) + cqo;
        __builtin_nontemporal_store(o, (vf4*)(ob + po));
    }
}

extern "C" void kernel_launch(void* const* d_in, const int* in_sizes, int n_in,
                              void* d_out, int out_size, void* d_ws, size_t ws_size,
                              hipStream_t stream) {
    const float* x     = (const float*)d_in[0];   // (16,256,256,16) f32
    const float* W_loc = (const float*)d_in[1];   // (16,6) f32
    const float* b_loc = (const float*)d_in[2];   // (6,) f32
    // d_in[3] = coords_grid == np.indices((256,256)) -> recomputed on-chip.

    float4* part = (float4*)d_ws;                             // 2048*4 float4 = 128 KB
    float*  prm  = (float*)((char*)d_ws + 2048 * 4 * sizeof(float4)); // 16*8 floats

    pool_partial<<<POOL_BLOCKS, 256, 0, stream>>>((const float4*)x, part);
    params_kernel<<<BB, 256, 0, stream>>>(part, W_loc, b_loc, prm);
    sample_v2<<<SAMPLE_BLOCKS, 256, 0, stream>>>((const char*)x, prm, (char*)d_out);
}

// Round 3
// 127.421 us; speedup vs baseline: 1.0470x; 1.0470x over previous
//
#include <hip/hip_runtime.h>

// Problem constants: B,H,W,C = 16,256,256,16 ; HO,WO = 256,256
#define BB 16
#define HH 256
#define WW 256
#define CC 16
#define NPIX (HH * WW)            // 65536 pixels per batch

// Pool: 1024 blocks (64/batch), 256 threads; block reduces a contiguous
// 64 KB slice (4096 float4) to 16 channel sums (4 float4).
#define POOL_BLOCKS 1024
// Sample: 1024 blocks (64/batch), 256 threads; block = 1024 pixels (4 rows).
#define SAMPLE_BLOCKS 1024

typedef float vf4 __attribute__((ext_vector_type(4)));

// ---------------------------------------------------------------------------
// Kernel 1: partial mean-pool. Thread t reads 16 float4 at stride 256
// (coalesced); float4 index mod 4 == t mod 4, so lanes with equal (lane&3)
// share a channel quad -> shuffle-down by 4.. reduces within the wave.
// Output: part[blk*4 + q] ; batch b owns part[b*256 .. b*256+256) float4.
// ---------------------------------------------------------------------------
__global__ __launch_bounds__(256) void pool_partial(const float4* __restrict__ x4,
                                                    float4* __restrict__ part) {
    const int blk = blockIdx.x;
    const int tid = threadIdx.x;
    const float4* p = x4 + (size_t)blk * 4096 + tid;
    float4 acc = {0.f, 0.f, 0.f, 0.f};
#pragma unroll
    for (int k = 0; k < 16; ++k) {
        float4 v = p[k * 256];
        acc.x += v.x; acc.y += v.y; acc.z += v.z; acc.w += v.w;
    }
    for (int off = 4; off < 64; off <<= 1) {
        acc.x += __shfl_down(acc.x, off);
        acc.y += __shfl_down(acc.y, off);
        acc.z += __shfl_down(acc.z, off);
        acc.w += __shfl_down(acc.w, off);
    }
    __shared__ float4 wsum[4][4];
    const int wave = tid >> 6, lane = tid & 63;
    if (lane < 4) wsum[wave][lane] = acc;
    __syncthreads();
    if (tid < 4) {
        float4 t0 = wsum[0][tid], t1 = wsum[1][tid];
        float4 t2 = wsum[2][tid], t3 = wsum[3][tid];
        float4 t;
        t.x = t0.x + t1.x + t2.x + t3.x;
        t.y = t0.y + t1.y + t2.y + t3.y;
        t.z = t0.z + t1.z + t2.z + t3.z;
        t.w = t0.w + t1.w + t2.w + t3.w;
        part[blk * 4 + tid] = t;
    }
}

// ---------------------------------------------------------------------------
// Kernel 2: lean params prologue (4 KB read + shuffle reduce + 16x6 matmul),
// then bilinear sampling. 1024 blocks, 256 threads; block = 1024 pixels
// (4 output rows) of one batch; 4 lanes per pixel (one float4 channel quad
// each); 16 pixel-quads per thread.
//  - 32-bit byte offsets off a wave-uniform batch base (SGPR base + VGPR
//    voffset loads; offsets < 4 MiB).
//  - non-temporal stores: output is write-once, keep it out of the caches
//    the x gathers hit.
// ---------------------------------------------------------------------------
__global__ __launch_bounds__(256) void sample_fused(
    const char*  __restrict__ xb0,
    const float* __restrict__ W_loc,
    const float* __restrict__ b_loc,
    const float4* __restrict__ part,
    char*        __restrict__ ob0)
{
    const int tid  = threadIdx.x;
    const int blk  = blockIdx.x;       // b*64 + loc
    const int b    = blk >> 6;
    const int loc  = blk & 63;
    const int wave = tid >> 6, lane = tid & 63;

    __shared__ float4 wsum[4][4];
    __shared__ float  pooled[CC];
    __shared__ float  prs[6];

    // ---- params prologue: reduce this batch's 256 float4 partials ----
    {
        const float4* q = part + (size_t)b * 256;
        float4 acc = q[tid];           // one partial per thread; cq = tid&3
        for (int off = 4; off < 64; off <<= 1) {
            acc.x += __shfl_down(acc.x, off);
            acc.y += __shfl_down(acc.y, off);
            acc.z += __shfl_down(acc.z, off);
            acc.w += __shfl_down(acc.w, off);
        }
        if (lane < 4) wsum[wave][lane] = acc;
        __syncthreads();
        if (tid < 4) {
            float4 t0 = wsum[0][tid], t1 = wsum[1][tid];
            float4 t2 = wsum[2][tid], t3 = wsum[3][tid];
            pooled[tid * 4 + 0] = (t0.x + t1.x + t2.x + t3.x) * (1.0f / 65536.0f);
            pooled[tid * 4 + 1] = (t0.y + t1.y + t2.y + t3.y) * (1.0f / 65536.0f);
            pooled[tid * 4 + 2] = (t0.z + t1.z + t2.z + t3.z) * (1.0f / 65536.0f);
            pooled[tid * 4 + 3] = (t0.w + t1.w + t2.w + t3.w) * (1.0f / 65536.0f);
        }
        __syncthreads();
        if (tid < 6) {
            float a = b_loc[tid];
#pragma unroll
            for (int c = 0; c < CC; ++c)
                a += pooled[c] * W_loc[c * 6 + tid];
            prs[tid] = a;
        }
        __syncthreads();
    }

    // ---- bilinear sampling: 16 pixel-quads per thread ----
    const float p0 = prs[0], p1 = prs[1], p2 = prs[2];
    const float p3 = prs[3], p4 = prs[4], p5 = prs[5];

    const char* xb = xb0 + ((size_t)b << 22);   // 4 MiB per batch
    char*       ob = ob0 + ((size_t)b << 22);
    const unsigned int cqo = (unsigned int)(tid & 3) << 4;
    const int pixBase = loc * 1024 + (tid >> 2);

#pragma unroll 4
    for (int k = 0; k < 16; ++k) {
        const int pix = pixBase + k * 64;
        const int hh  = pix >> 8;
        const int wpx = pix & 255;

        const float fh = (float)hh, fw = (float)wpx;
        const float yc = p0 * fh + p1 * fw + p4;
        const float xc = p2 * fh + p3 * fw + p5;

        const float y0f = floorf(yc), x0f = floorf(xc);
        const float wy = yc - y0f, wx = xc - x0f;
        const int y0 = (int)y0f, x0v = (int)x0f;
        const int y0i = min(max(y0,     0), HH - 1);
        const int y1i = min(max(y0 + 1, 0), HH - 1);
        const int x0i = min(max(x0v,     0), WW - 1);
        const int x1i = min(max(x0v + 1, 0), WW - 1);

        const unsigned int r0 = ((unsigned int)y0i << 14) + cqo;  // y*W*C*4
        const unsigned int r1 = ((unsigned int)y1i << 14) + cqo;
        const unsigned int c0 = (unsigned int)x0i << 6;           // x*C*4
        const unsigned int c1 = (unsigned int)x1i << 6;

        const vf4 Ia = *(const vf4*)(xb + (r0 + c0));
        const vf4 Ib = *(const vf4*)(xb + (r0 + c1));
        const vf4 Ic = *(const vf4*)(xb + (r1 + c0));
        const vf4 Id = *(const vf4*)(xb + (r1 + c1));

        const float omy = 1.f - wy, omx = 1.f - wx;
        const float wa = omy * omx, wb_ = omy * wx;
        const float wc_ = wy * omx, wd = wy * wx;

        vf4 o = wa * Ia + wb_ * Ib + wc_ * Ic + wd * Id;

        const unsigned int po = ((unsigned int)pix << 6) + cqo;
        __builtin_nontemporal_store(o, (vf4*)(ob + po));
    }
}

extern "C" void kernel_launch(void* const* d_in, const int* in_sizes, int n_in,
                              void* d_out, int out_size, void* d_ws, size_t ws_size,
                              hipStream_t stream) {
    const float* x     = (const float*)d_in[0];   // (16,256,256,16) f32
    const float* W_loc = (const float*)d_in[1];   // (16,6) f32
    const float* b_loc = (const float*)d_in[2];   // (6,) f32
    // d_in[3] = coords_grid == np.indices((256,256)) -> recomputed on-chip.

    float4* part = (float4*)d_ws;                 // 1024*4 float4 = 64 KB

    pool_partial<<<POOL_BLOCKS, 256, 0, stream>>>((const float4*)x, part);
    sample_fused<<<SAMPLE_BLOCKS, 256, 0, stream>>>((const char*)x, W_loc, b_loc,
                                                    part, (char*)d_out);
}

// Round 4
// 125.460 us; speedup vs baseline: 1.0634x; 1.0156x over previous
//
#include <hip/hip_runtime.h>

// Problem constants: B,H,W,C = 16,256,256,16 ; HO,WO = 256,256
#define BB 16
#define HH 256
#define WW 256
#define CC 16
#define NPIX (HH * WW)            // 65536 pixels per batch

// Pool: 1024 blocks (64/batch), 256 threads; block reduces a contiguous
// 64 KB slice (4096 float4) to 16 channel sums (4 float4).
#define POOL_BLOCKS 1024
// Sample: 1024 blocks (64/batch), 256 threads; block = 1024 pixels (4 rows).
#define SAMPLE_BLOCKS 1024

typedef float vf4 __attribute__((ext_vector_type(4)));

// ---------------------------------------------------------------------------
// Kernel 1: partial mean-pool. Thread t reads 16 float4 at stride 256
// (coalesced); float4 index mod 4 == t mod 4, so lanes with equal (lane&3)
// share a channel quad -> shuffle-down by 4.. reduces within the wave.
// Output: part[blk*4 + q] ; batch b owns part[b*256 .. b*256+256) float4.
// ---------------------------------------------------------------------------
__global__ __launch_bounds__(256) void pool_partial(const float4* __restrict__ x4,
                                                    float4* __restrict__ part) {
    const int blk = blockIdx.x;
    const int tid = threadIdx.x;
    const float4* p = x4 + (size_t)blk * 4096 + tid;
    float4 acc = {0.f, 0.f, 0.f, 0.f};
#pragma unroll
    for (int k = 0; k < 16; ++k) {
        float4 v = p[k * 256];
        acc.x += v.x; acc.y += v.y; acc.z += v.z; acc.w += v.w;
    }
    for (int off = 4; off < 64; off <<= 1) {
        acc.x += __shfl_down(acc.x, off);
        acc.y += __shfl_down(acc.y, off);
        acc.z += __shfl_down(acc.z, off);
        acc.w += __shfl_down(acc.w, off);
    }
    __shared__ float4 wsum[4][4];
    const int wave = tid >> 6, lane = tid & 63;
    if (lane < 4) wsum[wave][lane] = acc;
    __syncthreads();
    if (tid < 4) {
        float4 t0 = wsum[0][tid], t1 = wsum[1][tid];
        float4 t2 = wsum[2][tid], t3 = wsum[3][tid];
        float4 t;
        t.x = t0.x + t1.x + t2.x + t3.x;
        t.y = t0.y + t1.y + t2.y + t3.y;
        t.z = t0.z + t1.z + t2.z + t3.z;
        t.w = t0.w + t1.w + t2.w + t3.w;
        part[blk * 4 + tid] = t;
    }
}

// ---------------------------------------------------------------------------
// Kernel 2: lean params prologue (4 KB read + shuffle reduce + 16x6 matmul),
// then bilinear sampling. 1024 blocks, 256 threads; block = 1024 pixels
// (4 output rows) of one batch; 4 lanes per pixel (one float4 channel quad
// each); 16 pixel-quads per thread.
//  - Loop order: w-chunk OUTER, row INNER. Ic/Id of row h become Ia/Ib of
//    row h+1 on the next iteration -> L1 reuse distance 1 iter (~2 KB/wave)
//    instead of 4 iters (~32 KB across 4 waves = L1-size, thrash). Pure
//    iteration reorder: per-pixel arithmetic bit-identical (absmax must not
//    move).
//  - w-dependent affine term hoisted as explicit fmaf nesting (bit-identical
//    to the contracted form of p0*fh + p1*fw + p4).
//  - 32-bit byte offsets off a wave-uniform batch base (SGPR base + VGPR
//    voffset loads; offsets < 4 MiB).
//  - non-temporal stores: output is write-once, keep it out of the caches
//    the x gathers hit.
// ---------------------------------------------------------------------------
__global__ __launch_bounds__(256) void sample_fused(
    const char*  __restrict__ xb0,
    const float* __restrict__ W_loc,
    const float* __restrict__ b_loc,
    const float4* __restrict__ part,
    char*        __restrict__ ob0)
{
    const int tid  = threadIdx.x;
    const int blk  = blockIdx.x;       // b*64 + loc
    const int b    = blk >> 6;
    const int loc  = blk & 63;
    const int wave = tid >> 6, lane = tid & 63;

    __shared__ float4 wsum[4][4];
    __shared__ float  pooled[CC];
    __shared__ float  prs[6];

    // ---- params prologue: reduce this batch's 256 float4 partials ----
    {
        const float4* q = part + (size_t)b * 256;
        float4 acc = q[tid];           // one partial per thread; cq = tid&3
        for (int off = 4; off < 64; off <<= 1) {
            acc.x += __shfl_down(acc.x, off);
            acc.y += __shfl_down(acc.y, off);
            acc.z += __shfl_down(acc.z, off);
            acc.w += __shfl_down(acc.w, off);
        }
        if (lane < 4) wsum[wave][lane] = acc;
        __syncthreads();
        if (tid < 4) {
            float4 t0 = wsum[0][tid], t1 = wsum[1][tid];
            float4 t2 = wsum[2][tid], t3 = wsum[3][tid];
            pooled[tid * 4 + 0] = (t0.x + t1.x + t2.x + t3.x) * (1.0f / 65536.0f);
            pooled[tid * 4 + 1] = (t0.y + t1.y + t2.y + t3.y) * (1.0f / 65536.0f);
            pooled[tid * 4 + 2] = (t0.z + t1.z + t2.z + t3.z) * (1.0f / 65536.0f);
            pooled[tid * 4 + 3] = (t0.w + t1.w + t2.w + t3.w) * (1.0f / 65536.0f);
        }
        __syncthreads();
        if (tid < 6) {
            float a = b_loc[tid];
#pragma unroll
            for (int c = 0; c < CC; ++c)
                a += pooled[c] * W_loc[c * 6 + tid];
            prs[tid] = a;
        }
        __syncthreads();
    }

    // ---- bilinear sampling: 16 pixel-quads per thread, h-inner order ----
    const float p0 = prs[0], p1 = prs[1], p2 = prs[2];
    const float p3 = prs[3], p4 = prs[4], p5 = prs[5];

    const char* xb = xb0 + ((size_t)b << 22);   // 4 MiB per batch
    char*       ob = ob0 + ((size_t)b << 22);
    const unsigned int cqo = (unsigned int)(tid & 3) << 4;
    const int h0 = loc * 4;
    const int w0 = tid >> 2;

#pragma unroll 2
    for (int kw = 0; kw < 4; ++kw) {
        const int   wpx = w0 + (kw << 6);
        const float fw  = (float)wpx;
        const float yw  = fmaf(p1, fw, p4);   // w-dependent terms hoisted;
        const float xw  = fmaf(p3, fw, p5);   // fmaf nesting == contracted form

#pragma unroll
        for (int kh = 0; kh < 4; ++kh) {
            const int hh  = h0 + kh;
            const int pix = (hh << 8) + wpx;

            const float fh = (float)hh;
            const float yc = fmaf(p0, fh, yw);
            const float xc = fmaf(p2, fh, xw);

            const float y0f = floorf(yc), x0f = floorf(xc);
            const float wy = yc - y0f, wx = xc - x0f;
            const int y0 = (int)y0f, x0v = (int)x0f;
            const int y0i = min(max(y0,     0), HH - 1);
            const int y1i = min(max(y0 + 1, 0), HH - 1);
            const int x0i = min(max(x0v,     0), WW - 1);
            const int x1i = min(max(x0v + 1, 0), WW - 1);

            const unsigned int r0 = ((unsigned int)y0i << 14) + cqo;  // y*W*C*4
            const unsigned int r1 = ((unsigned int)y1i << 14) + cqo;
            const unsigned int c0 = (unsigned int)x0i << 6;           // x*C*4
            const unsigned int c1 = (unsigned int)x1i << 6;

            const vf4 Ia = *(const vf4*)(xb + (r0 + c0));
            const vf4 Ib = *(const vf4*)(xb + (r0 + c1));
            const vf4 Ic = *(const vf4*)(xb + (r1 + c0));
            const vf4 Id = *(const vf4*)(xb + (r1 + c1));

            const float omy = 1.f - wy, omx = 1.f - wx;
            const float wa = omy * omx, wb_ = omy * wx;
            const float wc_ = wy * omx, wd = wy * wx;

            vf4 o = wa * Ia + wb_ * Ib + wc_ * Ic + wd * Id;

            const unsigned int po = ((unsigned int)pix << 6) + cqo;
            __builtin_nontemporal_store(o, (vf4*)(ob + po));
        }
    }
}

extern "C" void kernel_launch(void* const* d_in, const int* in_sizes, int n_in,
                              void* d_out, int out_size, void* d_ws, size_t ws_size,
                              hipStream_t stream) {
    const float* x     = (const float*)d_in[0];   // (16,256,256,16) f32
    const float* W_loc = (const float*)d_in[1];   // (16,6) f32
    const float* b_loc = (const float*)d_in[2];   // (6,) f32
    // d_in[3] = coords_grid == np.indices((256,256)) -> recomputed on-chip.

    float4* part = (float4*)d_ws;                 // 1024*4 float4 = 64 KB

    pool_partial<<<POOL_BLOCKS, 256, 0, stream>>>((const float4*)x, part);
    sample_fused<<<SAMPLE_BLOCKS, 256, 0, stream>>>((const char*)x, W_loc, b_loc,
                                                    part, (char*)d_out);
}